// Round 12
// baseline (82.688 us; speedup 1.0000x reference)
//
#include <hip/hip_runtime.h>
#include <math.h>

#define N_MID 62
#define NPAIR 31
#define BATCH 32768
#define NCHUNK (NPAIR * 4 * 64)  // 7936 u32x4 = 124 KB

typedef float f32x4 __attribute__((ext_vector_type(4)));
typedef unsigned int u32x2 __attribute__((ext_vector_type(2)));
typedef unsigned int u32x4 __attribute__((ext_vector_type(4)));

__device__ __forceinline__ long mklong(unsigned a, unsigned b) {
    u32x2 t = {a, b};
    return __builtin_bit_cast(long, t);
}
// pack 4 fp32 -> dword of 4 fp8 e4m3 (bytes 0..3 = a,b,c,d)
__device__ __forceinline__ unsigned pack_fp8x4(float a, float b, float c, float d) {
    int r = __builtin_amdgcn_cvt_pk_fp8_f32(a, b, 0, false);
    r = __builtin_amdgcn_cvt_pk_fp8_f32(c, d, r, true);
    return (unsigned)r;
}

// ---- Prefix: site-pair products T[2i][v0]*T[2i+1][v1] as fp8 A-frags ------
// Block = (pair i)*4 + variant v (v0=v&1 site 2i, v1=v>>1 site 2i+1).
// MFMA fp8 16x16x32 A-layout: lane l holds A[m=l&15][k=(l>>4)*8+j] in byte j.
// We store A_t[m,k] = P[lam(k)][16t+m], lam(8q+j)=16*(j>>2)+4q+(j&3), so the
// main loop's D->B handoff is purely in-lane (slot j=4t+r <- y_t[r]).
__global__ __launch_bounds__(64) void prefix_kernel(const float* __restrict__ t_mid,
                                                    unsigned* __restrict__ wsP) {
    __shared__ float M1s[1024], M2s[1024];
    const int l = threadIdx.x, q = l >> 4, m = l & 15;
    const int i = blockIdx.x >> 2, v = blockIdx.x & 3;

    const float4* s1 = (const float4*)(t_mid + (size_t)((2 * i) * 2 + (v & 1)) * 1024);
    const float4* s2 = (const float4*)(t_mid + (size_t)((2 * i + 1) * 2 + (v >> 1)) * 1024);
    #pragma unroll
    for (int c = 0; c < 4; ++c) {
        ((float4*)M1s)[c * 64 + l] = s1[c * 64 + l];
        ((float4*)M2s)[c * 64 + l] = s2[c * 64 + l];
    }
    __syncthreads();

    float colv[2][32];
    #pragma unroll
    for (int t = 0; t < 2; ++t)
        #pragma unroll
        for (int mm = 0; mm < 32; ++mm)
            colv[t][mm] = M2s[mm * 32 + 16 * t + m];

    float o0[8], o1[8];
    #pragma unroll
    for (int j = 0; j < 8; ++j) {
        int a = 16 * (j >> 2) + 4 * q + (j & 3);  // lam(8q+j)
        float acc0 = 0.f, acc1 = 0.f;
        #pragma unroll
        for (int mm = 0; mm < 32; ++mm) {
            float r = M1s[a * 32 + mm];
            acc0 = fmaf(r, colv[0][mm], acc0);
            acc1 = fmaf(r, colv[1][mm], acc1);
        }
        o0[j] = acc0;
        o1[j] = acc1;
    }

    u32x4 outw;
    outw[0] = pack_fp8x4(o0[0], o0[1], o0[2], o0[3]);
    outw[1] = pack_fp8x4(o0[4], o0[5], o0[6], o0[7]);
    outw[2] = pack_fp8x4(o1[0], o1[1], o1[2], o1[3]);
    outw[3] = pack_fp8x4(o1[4], o1[5], o1[6], o1[7]);
    ((u32x4*)wsP)[blockIdx.x * 64 + l] = outw;
}

// ---------------------------- Main MFMA kernel -----------------------------
// 512-thread blocks (8 waves), grid 256 = 1 block/CU (2 waves/SIMD). The
// ENTIRE pair-frag table (124 KB) is cooperatively staged into LDS once,
// one barrier, then the 31-step loop runs LDS-only (conflict-free b128).
// One wave = 16 batch elements; state = fp8 B-frag (2 dwords), component
// lam(8q+j) in byte j of lane (q,e). Per step: 4 per-element-masked B
// copies, 8 accumulating fp8 MFMAs, pow2 rescale every step (fp8 pack NaNs
// above 448 — r10), exact log bookkeeping, repack.
__global__ __launch_bounds__(512, 2) void mps_mfma_kernel(
    const float* __restrict__ t_first,
    const float* __restrict__ t_last,
    const int*   __restrict__ x,
    const unsigned* __restrict__ wsP,
    float* __restrict__ out)
{
    __shared__ u32x4 LP[NCHUNK];  // 124 KB: step i, variant v, lane l

    const int tid  = threadIdx.x;
    const int w    = tid >> 6;
    const int l    = tid & 63;
    const int q    = l >> 4;
    const int e    = l & 15;
    const int base = (blockIdx.x * 8 + w) * 16;

    // ---- Stage full frag table into LDS (16 chunks/thread). ----
    {
        const u32x4* src = (const u32x4*)wsP;
        for (int i = tid; i < NCHUNK; i += 512)
            LP[i] = src[i];
    }

    // ---- Inline spin mask for element e (overlaps with staging). ----
    unsigned long long mask;
    {
        const int4* xr = (const int4*)(x + (size_t)(base + e) * 64 + 16 * q);
        unsigned chunk = 0;
        #pragma unroll
        for (int c = 0; c < 4; ++c) {
            int4 vv = xr[c];
            chunk |= (unsigned)(vv.x > 0) << (4 * c + 0);
            chunk |= (unsigned)(vv.y > 0) << (4 * c + 1);
            chunk |= (unsigned)(vv.z > 0) << (4 * c + 2);
            chunk |= (unsigned)(vv.w > 0) << (4 * c + 3);
        }
        unsigned sh = chunk << ((q & 1) * 16);
        unsigned lo = (q < 2) ? sh : 0u;
        unsigned hi = (q >= 2) ? sh : 0u;
        lo |= (unsigned)__shfl_xor((int)lo, 16);
        lo |= (unsigned)__shfl_xor((int)lo, 32);
        hi |= (unsigned)__shfl_xor((int)hi, 16);
        hi |= (unsigned)__shfl_xor((int)hi, 32);
        mask = ((unsigned long long)hi << 32) | lo;
    }

    // ---- Init state (B-frag component order) from t_first[bit0]. ----
    float st[8];
    {
        const float* tf = t_first + ((mask & 1ull) ? 32 : 0);
        #pragma unroll
        for (int j = 0; j < 8; ++j)
            st[j] = tf[16 * (j >> 2) + 4 * q + (j & 3)];
    }
    unsigned long long mrot = mask >> 1;  // pairs consume bits 1..62; bit63 = t_last
    unsigned Bd0 = pack_fp8x4(st[0], st[1], st[2], st[3]);
    unsigned Bd1 = pack_fp8x4(st[4], st[5], st[6], st[7]);

    int expsum = 0;
    const f32x4 cz = {0.f, 0.f, 0.f, 0.f};

    __syncthreads();  // staging complete (once)

    // 2-step rolling prefetch out of LDS.
    u32x4 Q0[4], Q1[4];
    #pragma unroll
    for (int v = 0; v < 4; ++v) Q0[v] = LP[v * 64 + l];
    #pragma unroll
    for (int v = 0; v < 4; ++v) Q1[v] = LP[(4 + v) * 64 + l];

    auto step = [&](u32x4* Q, int pfIdx) {
        unsigned vl = (unsigned)mrot & 3u;
        mrot >>= 2;

        f32x4 y0 = cz, y1 = cz;
        #pragma unroll
        for (int v = 0; v < 4; ++v) {
            long A0 = mklong(Q[v][0], Q[v][1]);   // tile 0
            long A1 = mklong(Q[v][2], Q[v][3]);   // tile 1
            bool sel = (vl == (unsigned)v);
            long u = mklong(sel ? Bd0 : 0u, sel ? Bd1 : 0u);
            y0 = __builtin_amdgcn_mfma_f32_16x16x32_fp8_fp8(A0, u, y0, 0, 0, 0);
            y1 = __builtin_amdgcn_mfma_f32_16x16x32_fp8_fp8(A1, u, y1, 0, 0, 0);
        }

        if (pfIdx >= 0) {
            #pragma unroll
            for (int v = 0; v < 4; ++v) Q[v] = LP[pfIdx + v * 64 + l];
        }

        #pragma unroll
        for (int r = 0; r < 4; ++r) { st[r] = y0[r]; st[4 + r] = y1[r]; }

        // per-element pow2 rescale (MANDATORY every step: fp8 pack NaNs >448)
        float mx = st[0];
        #pragma unroll
        for (int j = 1; j < 8; ++j) mx = fmaxf(mx, st[j]);
        mx = fmaxf(mx, __shfl_xor(mx, 16));
        mx = fmaxf(mx, __shfl_xor(mx, 32));
        int ex = (int)((__float_as_uint(mx) >> 23) & 0xFF) - 127;
        float sc = __uint_as_float((unsigned)(127 - ex) << 23);
        #pragma unroll
        for (int j = 0; j < 8; ++j) st[j] *= sc;
        expsum += ex;

        Bd0 = pack_fp8x4(st[0], st[1], st[2], st[3]);
        Bd1 = pack_fp8x4(st[4], st[5], st[6], st[7]);
    };

    for (int k = 0; k < 15; ++k) {
        step(Q0, (2 * k + 2) * 256);                            // step 2k
        step(Q1, (k < 14) ? (2 * k + 3) * 256 : -1);            // step 2k+1
    }
    step(Q0, -1);  // step 30

    // ---- Epilogue: amp = dot(state, t_last[bit63]); reduce over q. ----
    const float* tl = t_last + ((mrot & 1ull) ? 32 : 0);
    float amp = 0.f;
    #pragma unroll
    for (int j = 0; j < 8; ++j)
        amp = fmaf(st[j], tl[16 * (j >> 2) + 4 * q + (j & 3)], amp);
    amp += __shfl_xor(amp, 16);
    amp += __shfl_xor(amp, 32);

    if (l < 16)
        out[base + l] = logf(amp) + 0.69314718055994531f * (float)expsum;
}

extern "C" void kernel_launch(void* const* d_in, const int* in_sizes, int n_in,
                              void* d_out, int out_size, void* d_ws, size_t ws_size,
                              hipStream_t stream) {
    const float* t_first = (const float*)d_in[0];
    const float* t_mid   = (const float*)d_in[1];
    const float* t_last  = (const float*)d_in[2];
    const int*   x       = (const int*)d_in[3];
    float* out           = (float*)d_out;

    unsigned* wsP = (unsigned*)d_ws;  // 31 pairs x 4 variants x 1 KB = 124 KB

    hipLaunchKernelGGL(prefix_kernel, dim3(NPAIR * 4), dim3(64), 0, stream, t_mid, wsP);
    hipLaunchKernelGGL(mps_mfma_kernel, dim3(BATCH / 128), dim3(512), 0, stream,
                       t_first, t_last, x, wsP, out);
}

// Round 13
// 78.186 us; speedup vs baseline: 1.0576x; 1.0576x over previous
//
#include <hip/hip_runtime.h>
#include <math.h>

#define N_MID 62
#define NPAIR 31
#define BATCH 32768

typedef float f32x4 __attribute__((ext_vector_type(4)));
typedef unsigned int u32x2 __attribute__((ext_vector_type(2)));
typedef unsigned int u32x4 __attribute__((ext_vector_type(4)));

__device__ __forceinline__ long mklong(unsigned a, unsigned b) {
    u32x2 t = {a, b};
    return __builtin_bit_cast(long, t);
}
// pack 4 fp32 -> dword of 4 fp8 e4m3 (bytes 0..3 = a,b,c,d)
__device__ __forceinline__ unsigned pack_fp8x4(float a, float b, float c, float d) {
    int r = __builtin_amdgcn_cvt_pk_fp8_f32(a, b, 0, false);
    r = __builtin_amdgcn_cvt_pk_fp8_f32(c, d, r, true);
    return (unsigned)r;
}

// ---- Prefix: site-pair products T[2i][v0]*T[2i+1][v1] as fp8 A-frags ------
// Block = (pair i)*4 + variant v (v0=v&1 site 2i, v1=v>>1 site 2i+1).
// MFMA fp8 16x16x32 A-layout: lane l holds A[m=l&15][k=(l>>4)*8+j] in byte j.
// We store A_t[m,k] = P[lam(k)][16t+m], lam(8q+j)=16*(j>>2)+4q+(j&3), so the
// main loop's D->B handoff is purely in-lane (slot j=4t+r <- y_t[r]).
__global__ __launch_bounds__(64) void prefix_kernel(const float* __restrict__ t_mid,
                                                    unsigned* __restrict__ wsP) {
    __shared__ float M1s[1024], M2s[1024];
    const int l = threadIdx.x, q = l >> 4, m = l & 15;
    const int i = blockIdx.x >> 2, v = blockIdx.x & 3;

    const float4* s1 = (const float4*)(t_mid + (size_t)((2 * i) * 2 + (v & 1)) * 1024);
    const float4* s2 = (const float4*)(t_mid + (size_t)((2 * i + 1) * 2 + (v >> 1)) * 1024);
    #pragma unroll
    for (int c = 0; c < 4; ++c) {
        ((float4*)M1s)[c * 64 + l] = s1[c * 64 + l];
        ((float4*)M2s)[c * 64 + l] = s2[c * 64 + l];
    }
    __syncthreads();

    float colv[2][32];
    #pragma unroll
    for (int t = 0; t < 2; ++t)
        #pragma unroll
        for (int mm = 0; mm < 32; ++mm)
            colv[t][mm] = M2s[mm * 32 + 16 * t + m];

    float o0[8], o1[8];
    #pragma unroll
    for (int j = 0; j < 8; ++j) {
        int a = 16 * (j >> 2) + 4 * q + (j & 3);  // lam(8q+j)
        float acc0 = 0.f, acc1 = 0.f;
        #pragma unroll
        for (int mm = 0; mm < 32; ++mm) {
            float r = M1s[a * 32 + mm];
            acc0 = fmaf(r, colv[0][mm], acc0);
            acc1 = fmaf(r, colv[1][mm], acc1);
        }
        o0[j] = acc0;
        o1[j] = acc1;
    }

    u32x4 outw;
    outw[0] = pack_fp8x4(o0[0], o0[1], o0[2], o0[3]);
    outw[1] = pack_fp8x4(o0[4], o0[5], o0[6], o0[7]);
    outw[2] = pack_fp8x4(o1[0], o1[1], o1[2], o1[3]);
    outw[3] = pack_fp8x4(o1[4], o1[5], o1[6], o1[7]);
    ((u32x4*)wsP)[blockIdx.x * 64 + l] = outw;
}

// ---------------------------- Main MFMA kernel -----------------------------
// One wave = 16 batch elements (element = lane&15), no LDS, no barriers.
// State = fp8 B-frag (2 dwords): byte j of lane (q,e) holds component
// lam(8q+j) of element e. Per pair-step: 4 per-element-masked B copies
// (variant = 2 spin bits), 8 accumulating fp8 MFMAs (4 variants x 2 tiles),
// pow2 rescale every step (exact log bookkeeping; fp8 pack NaNs above 448
// so rescale cadence must stay 1), repack to fp8. 2-step rolling prefetch
// from L2. Empirically the optimum of rounds 2-12: every structural
// deviation (fewer waves, split chains, LDS table, sparse rescale) lost.
__global__ __launch_bounds__(256, 2) void mps_mfma_kernel(
    const float* __restrict__ t_first,
    const float* __restrict__ t_last,
    const int*   __restrict__ x,
    const unsigned* __restrict__ wsP,
    float* __restrict__ out)
{
    const int tid  = threadIdx.x;
    const int w    = tid >> 6;
    const int l    = tid & 63;
    const int q    = l >> 4;
    const int e    = l & 15;
    const int base = (blockIdx.x * 4 + w) * 16;

    // ---- Inline spin mask for element e: bit s = (x[base+e][s] > 0). ----
    unsigned long long mask;
    {
        const int4* xr = (const int4*)(x + (size_t)(base + e) * 64 + 16 * q);
        unsigned chunk = 0;
        #pragma unroll
        for (int c = 0; c < 4; ++c) {
            int4 vv = xr[c];
            chunk |= (unsigned)(vv.x > 0) << (4 * c + 0);
            chunk |= (unsigned)(vv.y > 0) << (4 * c + 1);
            chunk |= (unsigned)(vv.z > 0) << (4 * c + 2);
            chunk |= (unsigned)(vv.w > 0) << (4 * c + 3);
        }
        unsigned sh = chunk << ((q & 1) * 16);
        unsigned lo = (q < 2) ? sh : 0u;
        unsigned hi = (q >= 2) ? sh : 0u;
        lo |= (unsigned)__shfl_xor((int)lo, 16);
        lo |= (unsigned)__shfl_xor((int)lo, 32);
        hi |= (unsigned)__shfl_xor((int)hi, 16);
        hi |= (unsigned)__shfl_xor((int)hi, 32);
        mask = ((unsigned long long)hi << 32) | lo;
    }

    // ---- Init state (B-frag component order) from t_first[bit0]. ----
    float st[8];
    {
        const float* tf = t_first + ((mask & 1ull) ? 32 : 0);
        #pragma unroll
        for (int j = 0; j < 8; ++j)
            st[j] = tf[16 * (j >> 2) + 4 * q + (j & 3)];
    }
    unsigned long long mrot = mask >> 1;  // pairs consume bits 1..62; bit63 = t_last
    unsigned Bd0 = pack_fp8x4(st[0], st[1], st[2], st[3]);
    unsigned Bd1 = pack_fp8x4(st[4], st[5], st[6], st[7]);

    int expsum = 0;
    const f32x4 cz = {0.f, 0.f, 0.f, 0.f};

    // 2-step rolling prefetch of pair-frags: 4 variants x 16 B/lane per step.
    const u32x4* W = (const u32x4*)wsP + l;  // step i, variant v: + (i*4+v)*64
    u32x4 Q0[4], Q1[4];
    #pragma unroll
    for (int v = 0; v < 4; ++v) Q0[v] = W[v * 64];
    #pragma unroll
    for (int v = 0; v < 4; ++v) Q1[v] = W[(4 + v) * 64];

    auto step = [&](u32x4* Q, const u32x4* pf) {
        unsigned vl = (unsigned)mrot & 3u;
        mrot >>= 2;

        f32x4 y0 = cz, y1 = cz;
        #pragma unroll
        for (int v = 0; v < 4; ++v) {
            long A0 = mklong(Q[v][0], Q[v][1]);   // tile 0
            long A1 = mklong(Q[v][2], Q[v][3]);   // tile 1
            bool sel = (vl == (unsigned)v);
            long u = mklong(sel ? Bd0 : 0u, sel ? Bd1 : 0u);
            y0 = __builtin_amdgcn_mfma_f32_16x16x32_fp8_fp8(A0, u, y0, 0, 0, 0);
            y1 = __builtin_amdgcn_mfma_f32_16x16x32_fp8_fp8(A1, u, y1, 0, 0, 0);
        }

        if (pf) {
            #pragma unroll
            for (int v = 0; v < 4; ++v) Q[v] = pf[v * 64];
        }

        #pragma unroll
        for (int r = 0; r < 4; ++r) { st[r] = y0[r]; st[4 + r] = y1[r]; }

        // per-element pow2 rescale (exact log bookkeeping)
        float mx = st[0];
        #pragma unroll
        for (int j = 1; j < 8; ++j) mx = fmaxf(mx, st[j]);
        mx = fmaxf(mx, __shfl_xor(mx, 16));
        mx = fmaxf(mx, __shfl_xor(mx, 32));
        int ex = (int)((__float_as_uint(mx) >> 23) & 0xFF) - 127;
        float sc = __uint_as_float((unsigned)(127 - ex) << 23);
        #pragma unroll
        for (int j = 0; j < 8; ++j) st[j] *= sc;
        expsum += ex;

        Bd0 = pack_fp8x4(st[0], st[1], st[2], st[3]);
        Bd1 = pack_fp8x4(st[4], st[5], st[6], st[7]);
    };

    const u32x4* pf = W + 8 * 64;  // step-2 frags
    for (int k = 0; k < 15; ++k) {
        step(Q0, pf);                               // step 2k
        step(Q1, (k < 14) ? pf + 4 * 64 : nullptr); // step 2k+1
        pf += 8 * 64;
    }
    step(Q0, nullptr);  // step 30

    // ---- Epilogue: amp = dot(state, t_last[bit63]); reduce over q. ----
    const float* tl = t_last + ((mrot & 1ull) ? 32 : 0);
    float amp = 0.f;
    #pragma unroll
    for (int j = 0; j < 8; ++j)
        amp = fmaf(st[j], tl[16 * (j >> 2) + 4 * q + (j & 3)], amp);
    amp += __shfl_xor(amp, 16);
    amp += __shfl_xor(amp, 32);

    if (l < 16)
        out[base + l] = logf(amp) + 0.69314718055994531f * (float)expsum;
}

extern "C" void kernel_launch(void* const* d_in, const int* in_sizes, int n_in,
                              void* d_out, int out_size, void* d_ws, size_t ws_size,
                              hipStream_t stream) {
    const float* t_first = (const float*)d_in[0];
    const float* t_mid   = (const float*)d_in[1];
    const float* t_last  = (const float*)d_in[2];
    const int*   x       = (const int*)d_in[3];
    float* out           = (float*)d_out;

    unsigned* wsP = (unsigned*)d_ws;  // 31 pairs x 4 variants x 1 KB = 124 KB

    hipLaunchKernelGGL(prefix_kernel, dim3(NPAIR * 4), dim3(64), 0, stream, t_mid, wsP);
    hipLaunchKernelGGL(mps_mfma_kernel, dim3(BATCH / 64), dim3(256), 0, stream,
                       t_first, t_last, x, wsP, out);
}